// Round 4
// baseline (666.751 us; speedup 1.0000x reference)
//
#include <hip/hip_runtime.h>

// 2-layer GCN: h1 = emb[x] @ W1; agg+b1+relu; @ W2; agg+b2.
// R23: binned counting-sort CSR replaced by classic 3-pass ATOMIC CSR:
//   k_deg:     atomicAdd(deg[dst]) + atomicAdd(csum[dst>>7]) (fire-and-forget)
//   k_scan:    782 blocks; e0 = prefix-reduction over csum (R22 trick);
//              2-wave shfl scan of 128-node chunk -> row_start/cur/dinv;
//              fused mm1 (2 threads/node, R22 verbatim)
//   k_scatter3: col[atomicAdd(&cur[dst],1)] = src  -- no LDS, no packed array.
// Removes: packed 6.4MB write + 6.4MB read, 6.4M LDS atomics, LDS staging,
// one full dst re-read. Adds: 3.2M global atomics (avg contention 16/node,
// 2046/chunk -- independent L2 lines). Intra-node col order arbitrary (same
// numerics class as LDS-cursor nondeterminism). Aggs = R19/R22 verbatim.
// Rejected by measurement: LDS-atomic edge-parallel agg (R3); 16B-per-lane
// gathers (R10); channel-split passes (R7); cooperative fused build (R13);
// degree-sorted scheduling (R15); atomic-counter scan fusion w/ device fence
// (R16); one-node-per-wave agg (R20); launch-count reduction (R21: neutral).

#define BS   256
#define BSBIG 1024        // deg/scatter block size (16 waves)
#define NBLK 256          // blocks for deg/scatter
#define CHSHIFT 7         // 128 nodes per scan chunk
#define CH   128

union H2 { int i; _Float16 h[2]; };

// ---- pass 1: per-node degree + per-chunk totals (global atomics) ------------
__global__ __launch_bounds__(BSBIG) void k_deg(
    const int* __restrict__ dst, int E,
    int* __restrict__ deg, int* __restrict__ csum) {
    int t = threadIdx.x;
    int E4 = E >> 2;
    const int4* d4 = (const int4*)dst;
    for (int i = blockIdx.x * BSBIG + t; i < E4; i += NBLK * BSBIG) {
        int4 d = d4[i];
        atomicAdd(&deg[d.x], 1); atomicAdd(&csum[d.x >> CHSHIFT], 1);
        atomicAdd(&deg[d.y], 1); atomicAdd(&csum[d.y >> CHSHIFT], 1);
        atomicAdd(&deg[d.z], 1); atomicAdd(&csum[d.z >> CHSHIFT], 1);
        atomicAdd(&deg[d.w], 1); atomicAdd(&csum[d.w >> CHSHIFT], 1);
    }
    if (blockIdx.x == 0 && t < (E & 3)) {
        int d = dst[(E4 << 2) + t];
        atomicAdd(&deg[d], 1); atomicAdd(&csum[d >> CHSHIFT], 1);
    }
}

// ---- pass 2: CSR offsets (prefix-reduction + chunk scan) + fused mm1 --------
__global__ void k_scan(const int* __restrict__ deg, const int* __restrict__ csum,
                       int N, int E,
                       const int* __restrict__ x, const float* __restrict__ emb,
                       const float* __restrict__ W1,
                       int* __restrict__ row_start, int* __restrict__ cur,
                       float* __restrict__ dinv, _Float16* __restrict__ sig1) {
    __shared__ int ldeg[CH];
    __shared__ float sW[512];                    // W1 (16x32)
    __shared__ int redw[4];                      // e0 reduction
    __shared__ int wtot[2];                      // chunk-scan wave totals
    int b = blockIdx.x;
    int t = threadIdx.x;
    int lane = t & 63;
    int wv = t >> 6;
    int node0 = b << CHSHIFT;
    // e0 = sum of csum[0..b-1] (reduction; only one prefix needed per block)
    int ps = 0;
    for (int i = t; i < b; i += BS) ps += csum[i];
    #pragma unroll
    for (int off = 1; off < 64; off <<= 1) ps += __shfl_xor(ps, off);
    if (lane == 0) redw[wv] = ps;
    sW[t] = W1[t];                               // overlap with reduction
    sW[t + 256] = W1[t + 256];
    if (t < CH) {
        int n = node0 + t;
        ldeg[t] = (n < N) ? deg[n] : 0;
    }
    if (b == 0 && t == 0) row_start[N] = E;      // sentinel
    __syncthreads();
    int e0 = redw[0] + redw[1] + redw[2] + redw[3];
    // exclusive scan of ldeg[128] via 2-wave shfl scan (1 barrier)
    int myDeg = 0, inc = 0;
    if (t < CH) {
        myDeg = ldeg[t];
        inc = myDeg;
        #pragma unroll
        for (int off = 1; off < 64; off <<= 1) {
            int tmp = __shfl_up(inc, off);
            if (lane >= off) inc += tmp;
        }
        if (lane == 63) wtot[wv] = inc;
    }
    __syncthreads();
    if (t < CH) {
        int pre = (wv == 1) ? wtot[0] : 0;
        int ex = (inc - myDeg) + pre;
        int n = node0 + t;
        if (n < N) {
            row_start[n] = e0 + ex;
            cur[n]       = e0 + ex;              // scatter cursor init
            dinv[n] = rsqrtf((float)(myDeg + 1));
        }
    }
    // ---- fused mm1: 2 threads per node (16 channels each) ----
    int nl = t & (CH - 1);
    int half = t >> 7;                           // 0 or 1
    int n = node0 + nl;
    if (n < N) {
        float di = rsqrtf((float)(ldeg[nl] + 1));
        const float4* er = (const float4*)(emb + (size_t)x[n] * 16);
        float4 ra = er[0], rb = er[1], rc = er[2], rd = er[3];
        float ev[16] = {ra.x, ra.y, ra.z, ra.w, rb.x, rb.y, rb.z, rb.w,
                        rc.x, rc.y, rc.z, rc.w, rd.x, rd.y, rd.z, rd.w};
        int4* s1o = (int4*)sig1;
        #pragma unroll
        for (int cq2 = 0; cq2 < 2; cq2++) {
            int cq = half * 2 + cq2;
            H2 pk[4];
            #pragma unroll
            for (int dw = 0; dw < 4; dw++) {
                int c = cq * 8 + dw * 2;
                float acc0 = 0.f, acc1 = 0.f;
                #pragma unroll
                for (int k = 0; k < 16; k++) {
                    acc0 += ev[k] * sW[k * 32 + c];
                    acc1 += ev[k] * sW[k * 32 + c + 1];
                }
                pk[dw].h[0] = (_Float16)(acc0 * di);
                pk[dw].h[1] = (_Float16)(acc1 * di);
            }
            int4 pv;
            pv.x = pk[0].i; pv.y = pk[1].i; pv.z = pk[2].i; pv.w = pk[3].i;
            s1o[(size_t)n * 4 + cq] = pv;
        }
    }
}

// ---- pass 3: direct CSR scatter (global cursor atomics, no LDS) -------------
__global__ __launch_bounds__(BSBIG) void k_scatter3(
    const int* __restrict__ src, const int* __restrict__ dst, int E,
    int* __restrict__ cur, int* __restrict__ col) {
    int t = threadIdx.x;
    int E4 = E >> 2;
    const int4* s4 = (const int4*)src;
    const int4* d4 = (const int4*)dst;
    for (int i = blockIdx.x * BSBIG + t; i < E4; i += NBLK * BSBIG) {
        int4 s = s4[i];
        int4 d = d4[i];
        int p0 = atomicAdd(&cur[d.x], 1);
        int p1 = atomicAdd(&cur[d.y], 1);
        int p2 = atomicAdd(&cur[d.z], 1);
        int p3 = atomicAdd(&cur[d.w], 1);
        col[p0] = s.x;
        col[p1] = s.y;
        col[p2] = s.z;
        col[p3] = s.w;
    }
    if (blockIdx.x == 0 && t < (E & 3)) {
        int e = (E4 << 2) + t;
        int p = atomicAdd(&cur[dst[e]], 1);
        col[p] = src[e];
    }
}

// ---- fused layer-1 aggregate + b1 + relu + GEMM W2 -> sig2 (fp16) -----------
// 4 NODES per wave: lane = (node g in [0,4)) x (dword-channel cd in [0,16)).
// 8 edges/iter: 8 gathers in flight per lane; col prefetched one iter ahead.
__global__ __launch_bounds__(BS) void k_agg1mm2(
    const _Float16* __restrict__ sig1, const int* __restrict__ row_start,
    const float* __restrict__ dinv, const int* __restrict__ col,
    const float* __restrict__ b1, const float* __restrict__ W2,
    int N, _Float16* __restrict__ sig2) {
    __shared__ float hbuf[4][4][36];   // [wave][node][32 ch + pad]
    int t = threadIdx.x;
    int lane = t & 63;
    int wid = t >> 6;
    int g  = lane >> 4;                // node within wave
    int cd = lane & 15;                // dword channel (2 fp16)
    int n = blockIdx.x * 16 + wid * 4 + g;
    int nld = (n < N) ? n : N - 1;
    int rs = row_start[nld];
    int re = row_start[nld + 1];
    int dn = (n < N) ? (re - rs) : 0;
    int dnm1 = (dn > 0) ? dn - 1 : 0;
    int dm = dn;                       // wave max degree
    dm = max(dm, __shfl_xor(dm, 16));
    dm = max(dm, __shfl_xor(dm, 32));
    float w2c[32];
    #pragma unroll
    for (int k = 0; k < 32; k++) w2c[k] = W2[k * 16 + cd];
    const int* s1i = (const int*)sig1;
    float a0 = 0.f, a1 = 0.f;
    int iters = (dm + 7) >> 3;
    int slot = cd & 7;
    int bidx = lane & 48;              // group base lane
    int colv = 0;
    if (iters > 0) {
        int idx = slot; if (idx > dnm1) idx = dnm1;
        colv = col[rs + idx];
    }
    for (int it = 0; it < iters; it++) {
        int e = it << 3;
        int coln = 0;
        if (it + 1 < iters) {
            int idx = e + 8 + slot; if (idx > dnm1) idx = dnm1;
            coln = col[rs + idx];      // prefetch next round
        }
        int s0 = __shfl(colv, bidx + 0);
        int s1 = __shfl(colv, bidx + 1);
        int s2 = __shfl(colv, bidx + 2);
        int s3 = __shfl(colv, bidx + 3);
        int s4 = __shfl(colv, bidx + 4);
        int s5 = __shfl(colv, bidx + 5);
        int s6 = __shfl(colv, bidx + 6);
        int s7 = __shfl(colv, bidx + 7);
        int u0 = s1i[s0 * 16 + cd];    // 8 rows (64B lines) in flight
        int u1 = s1i[s1 * 16 + cd];
        int u2 = s1i[s2 * 16 + cd];
        int u3 = s1i[s3 * 16 + cd];
        int u4 = s1i[s4 * 16 + cd];
        int u5 = s1i[s5 * 16 + cd];
        int u6 = s1i[s6 * 16 + cd];
        int u7 = s1i[s7 * 16 + cd];
        u0 = (e + 0 < dn) ? u0 : 0;    // 0x0 == +0.0 fp16 pair
        u1 = (e + 1 < dn) ? u1 : 0;
        u2 = (e + 2 < dn) ? u2 : 0;
        u3 = (e + 3 < dn) ? u3 : 0;
        u4 = (e + 4 < dn) ? u4 : 0;
        u5 = (e + 5 < dn) ? u5 : 0;
        u6 = (e + 6 < dn) ? u6 : 0;
        u7 = (e + 7 < dn) ? u7 : 0;
        H2 p0, p1, p2, p3;
        p0.i = u0; p1.i = u1; p2.i = u2; p3.i = u3;
        a0 += ((float)p0.h[0] + (float)p1.h[0]) + ((float)p2.h[0] + (float)p3.h[0]);
        a1 += ((float)p0.h[1] + (float)p1.h[1]) + ((float)p2.h[1] + (float)p3.h[1]);
        p0.i = u4; p1.i = u5; p2.i = u6; p3.i = u7;
        a0 += ((float)p0.h[0] + (float)p1.h[0]) + ((float)p2.h[0] + (float)p3.h[0]);
        a1 += ((float)p0.h[1] + (float)p1.h[1]) + ((float)p2.h[1] + (float)p3.h[1]);
        colv = coln;
    }
    {   // self-loop (pre-scaled row)
        H2 p; p.i = s1i[nld * 16 + cd];
        a0 += (float)p.h[0];
        a1 += (float)p.h[1];
    }
    float di = dinv[nld];
    float2 b = ((const float2*)b1)[cd];
    float h0 = fmaxf(a0 * di + b.x, 0.f);
    float h1 = fmaxf(a1 * di + b.y, 0.f);
    float* hb = hbuf[wid][g];
    *(float2*)&hb[2 * cd] = make_float2(h0, h1);
    // same-wave LDS produce->consume: in-order ds ops + lgkmcnt, no barrier
    float a = 0.f;
    #pragma unroll
    for (int k = 0; k < 32; k += 4) {
        float4 hv = *(const float4*)&hb[k];
        a = fmaf(hv.x, w2c[k],     a);
        a = fmaf(hv.y, w2c[k + 1], a);
        a = fmaf(hv.z, w2c[k + 2], a);
        a = fmaf(hv.w, w2c[k + 3], a);
    }
    if (n < N) sig2[(size_t)n * 16 + cd] = (_Float16)(a * di);   // pre-scale
}

// ---- layer-2 aggregate + b2 -> out ------------------------------------------
// 4 NODES per wave: lane = (node g) x (edge-half e2) x (dword cd in [0,8)).
// 16 edges/iter: 8 gathers (8 rows each) in flight; col prefetch.
__global__ __launch_bounds__(BS) void k_agg2(
    const _Float16* __restrict__ sig2, const int* __restrict__ row_start,
    const float* __restrict__ dinv, const int* __restrict__ col,
    const float* __restrict__ b2, int N, float* __restrict__ out) {
    int t = threadIdx.x;
    int lane = t & 63;
    int g  = lane >> 4;                // node within wave
    int e2 = (lane >> 3) & 1;          // edge half
    int cd = lane & 7;                 // dword channel (2 fp16)
    int n = blockIdx.x * 16 + (t >> 6) * 4 + g;
    int nld = (n < N) ? n : N - 1;
    int rs = row_start[nld];
    int re = row_start[nld + 1];
    int dn = (n < N) ? (re - rs) : 0;
    int dnm1 = (dn > 0) ? dn - 1 : 0;
    int dm = dn;
    dm = max(dm, __shfl_xor(dm, 16));
    dm = max(dm, __shfl_xor(dm, 32));
    const int* s2i = (const int*)sig2;
    float a0 = 0.f, a1 = 0.f;
    int iters = (dm + 15) >> 4;
    int slot = lane & 15;              // this lane's col slot (0..15)
    int bidx = lane & 48;
    int colv = 0;
    if (iters > 0) {
        int idx = slot; if (idx > dnm1) idx = dnm1;
        colv = col[rs + idx];
    }
    for (int it = 0; it < iters; it++) {
        int e = it << 4;
        int coln = 0;
        if (it + 1 < iters) {
            int idx = e + 16 + slot; if (idx > dnm1) idx = dnm1;
            coln = col[rs + idx];      // prefetch next round
        }
        #pragma unroll
        for (int j = 0; j < 8; j++) {
            int sl = 2 * j + e2;
            int sv = __shfl(colv, bidx + sl);
            int u = s2i[sv * 8 + cd];  // 8 rows (32B) per inst
            u = (e + sl < dn) ? u : 0;
            H2 p; p.i = u;
            a0 += (float)p.h[0];
            a1 += (float)p.h[1];
        }
        colv = coln;
    }
    a0 += __shfl_xor(a0, 8);           // combine edge halves
    a1 += __shfl_xor(a1, 8);
    {   // self-loop
        H2 p; p.i = s2i[nld * 8 + cd];
        a0 += (float)p.h[0];
        a1 += (float)p.h[1];
    }
    if (n < N && e2 == 0) {
        float di = dinv[nld];
        float2 b = ((const float2*)b2)[cd];
        float2 o;
        o.x = a0 * di + b.x;
        o.y = a1 * di + b.y;
        ((float2*)out)[(size_t)n * 8 + cd] = o;
    }
}

extern "C" void kernel_launch(void* const* d_in, const int* in_sizes, int n_in,
                              void* d_out, int out_size, void* d_ws, size_t ws_size,
                              hipStream_t stream) {
    const int*   x   = (const int*)d_in[0];
    const int*   ei  = (const int*)d_in[1];
    const float* emb = (const float*)d_in[2];
    const float* W1  = (const float*)d_in[3];
    const float* b1  = (const float*)d_in[4];
    const float* W2  = (const float*)d_in[5];
    const float* b2  = (const float*)d_in[6];
    float* out = (float*)d_out;

    const int N = in_sizes[0];
    const int E = in_sizes[1] / 2;
    const int* srcp = ei;
    const int* dstp = ei + E;
    const int NCH = (N + CH - 1) >> CHSHIFT;       // 782 for N=100000

    auto al = [](size_t b) { return (b + 255) & ~size_t(255); };
    char* w = (char*)d_ws;
    auto carve = [&](size_t bytes) {
        void* p = (void*)w;
        w += al(bytes);
        return p;
    };
    int*   row_start = (int*)carve((size_t)(N + 1) * 4);
    float* dinv      = (float*)carve((size_t)N * 4);
    int*   col       = (int*)carve((size_t)(E + 256) * 4);
    int*   deg       = (int*)carve((size_t)N * 4);      // zeroed (with csum)
    int*   csum      = (int*)carve((size_t)NCH * 4);    // zeroed
    int*   cur       = (int*)carve((size_t)N * 4);
    _Float16* sig1   = (_Float16*)carve((size_t)N * 32 * 2);
    _Float16* sig2   = (_Float16*)carve((size_t)N * 16 * 2);
    (void)ws_size; (void)n_in; (void)out_size;

    size_t zbytes = (size_t)((char*)csum - (char*)deg) + (size_t)NCH * 4;
    hipMemsetAsync(deg, 0, zbytes, stream);
    k_deg<<<NBLK, BSBIG, 0, stream>>>(dstp, E, deg, csum);
    k_scan<<<NCH, BS, 0, stream>>>(deg, csum, N, E, x, emb, W1,
                                   row_start, cur, dinv, sig1);
    k_scatter3<<<NBLK, BSBIG, 0, stream>>>(srcp, dstp, E, cur, col);

    int gA = (N + 15) / 16;            // 4 waves x 4 nodes per block
    k_agg1mm2<<<gA, BS, 0, stream>>>(sig1, row_start, dinv, col, b1, W2, N, sig2);
    k_agg2<<<gA, BS, 0, stream>>>(sig2, row_start, dinv, col, b2, N, out);
}

// Round 5
// 147.612 us; speedup vs baseline: 4.5169x; 4.5169x over previous
//
#include <hip/hip_runtime.h>

// 2-layer GCN: h1 = emb[x] @ W1; agg+b1+relu; @ W2; agg+b2.
// CSR built per-launch via two-level binned counting sort (no global atomics
// per edge -- R23 measured why: atomic CSR k_deg alone = 429us, WRITE 89MB,
// VALUBusy 0.07%: random global atomics thrash the 8 incoherent L2s).
// R24 = R22 build (verbatim) + software-pipelined agg gathers: each agg iter
// now ISSUES the next group's 8 gathers before CONSUMING the current group's
// (col prefetched 2 groups ahead), so the compiler can wait at vmcnt(9)
// instead of draining -- breaks the iters x latency serialization. agg1's
// w2c (32 VGPR) load moved to epilogue (only used there; lowers loop
// pressure). Per-edge accumulation order unchanged (bit-identical absmax).
// Rejected by measurement: LDS-atomic edge-parallel agg (R3); 16B-per-lane
// gathers (R10); channel-split passes (R7); cooperative fused build (R13);
// degree-sorted scheduling (R15); atomic-counter scan fusion w/ device fence
// (R16); one-node-per-wave agg (R20); launch-count reduction (R21: neutral);
// global-atomic CSR (R23: 4.5x regression).

#define BS   256
#define BSBIG 1024        // scatter block size (16 waves)
#define NBLK 256          // blocks for scatter
#define BINSHIFT 7        // 128 nodes per bin
#define BIN  128
#define MAXBINS 1024
#define BINCAP 2560       // LDS packed staging (mean bin = 2046, sigma ~45)
#define BINSTRIDE 2560    // slack region per bin in packed (+11 sigma)

union H2 { int i; _Float16 h[2]; };

// ---- fused pass A+B+C: hist (LDS) -> global base alloc -> scatter ----------
// ONE packed 4B write per edge: src | dstLocal<<18  (src < 2^18), into
// per-bin slack regions packed[bin*BINSTRIDE ...]. gbin[i] accumulates bin
// totals via one atomicAdd per (block,bin).
__global__ __launch_bounds__(BSBIG) void k_scatter(
    const int* __restrict__ src, const int* __restrict__ dst,
    int E, int NBINS, int* __restrict__ gbin, int* __restrict__ packed) {
    __shared__ int h[MAXBINS];
    __shared__ int cur[MAXBINS];
    int t = threadIdx.x;
    for (int i = t; i < NBINS; i += BSBIG) h[i] = 0;
    __syncthreads();
    int E4 = E >> 2;
    const int4* d4 = (const int4*)dst;
    const int4* s4 = (const int4*)src;
    // phase 1: LDS histogram of this block's slice (+ tail on block 0)
    for (int i = blockIdx.x * BSBIG + t; i < E4; i += NBLK * BSBIG) {
        int4 d = d4[i];
        atomicAdd(&h[d.x >> BINSHIFT], 1);
        atomicAdd(&h[d.y >> BINSHIFT], 1);
        atomicAdd(&h[d.z >> BINSHIFT], 1);
        atomicAdd(&h[d.w >> BINSHIFT], 1);
    }
    if (blockIdx.x == 0 && t < (E & 3))
        atomicAdd(&h[dst[(E4 << 2) + t] >> BINSHIFT], 1);
    __syncthreads();
    // phase 2: one global atomicAdd per bin -> base within slack region
    for (int i = t; i < NBINS; i += BSBIG)
        cur[i] = i * BINSTRIDE + atomicAdd(&gbin[i], h[i]);
    __syncthreads();
    // phase 3: scatter (dst slice is L1/L2-hot from phase 1)
    for (int i = blockIdx.x * BSBIG + t; i < E4; i += NBLK * BSBIG) {
        int4 s = s4[i];
        int4 d = d4[i];
        int p0 = atomicAdd(&cur[d.x >> BINSHIFT], 1);
        packed[p0] = s.x | ((d.x & (BIN - 1)) << 18);
        int p1 = atomicAdd(&cur[d.y >> BINSHIFT], 1);
        packed[p1] = s.y | ((d.y & (BIN - 1)) << 18);
        int p2 = atomicAdd(&cur[d.z >> BINSHIFT], 1);
        packed[p2] = s.z | ((d.z & (BIN - 1)) << 18);
        int p3 = atomicAdd(&cur[d.w >> BINSHIFT], 1);
        packed[p3] = s.w | ((d.w & (BIN - 1)) << 18);
    }
    if (blockIdx.x == 0 && t < (E & 3)) {
        int e = (E4 << 2) + t;
        int d = dst[e];
        int p = atomicAdd(&cur[d >> BINSHIFT], 1);
        packed[p] = src[e] | ((d & (BIN - 1)) << 18);
    }
}

// ---- pass D: per-bin counting sort (staged in LDS) + fused mm1 --------------
// e0 (global CSR base for this bin) = prefix REDUCTION over gbin[0..b-1]
// (shfl tree + 1 barrier; full scan not needed -- only one prefix per block).
__global__ void k_binsort(const int* __restrict__ packed,
                          const int* __restrict__ gbin,
                          int NBINS, int N, int E,
                          const int* __restrict__ x, const float* __restrict__ emb,
                          const float* __restrict__ W1,
                          int* __restrict__ row_start, float* __restrict__ dinv,
                          int* __restrict__ col, _Float16* __restrict__ sig1) {
    __shared__ int buf[BINCAP];                  // 10 KB staging
    __shared__ int ldeg[BIN];
    __shared__ int cur[BIN];
    __shared__ float sW[512];                    // W1 (16x32)
    __shared__ int redw[4];                      // e0 reduction
    __shared__ int wtot[2];                      // ldeg scan wave totals
    int b = blockIdx.x;
    int t = threadIdx.x;
    int lane = t & 63;
    int wv = t >> 6;
    int node0 = b << BINSHIFT;
    // ---- e0 = sum of gbin[0..b-1] (reduction, not scan) ----
    int ps = 0;
    for (int i = t; i < b; i += BS) ps += gbin[i];
    #pragma unroll
    for (int off = 1; off < 64; off <<= 1) ps += __shfl_xor(ps, off);
    if (lane == 0) redw[wv] = ps;
    sW[t] = W1[t];                               // overlap with reduction
    sW[t + 256] = W1[t + 256];
    if (t < BIN) ldeg[t] = 0;
    if (b == 0 && t == 0) row_start[N] = E;      // sentinel
    __syncthreads();
    int e0 = redw[0] + redw[1] + redw[2] + redw[3];
    int cnt = gbin[b];
    int p0 = b * BINSTRIDE;                      // packed region base
    bool fits = (cnt <= BINCAP);                 // uniform per block
    if (fits)
        for (int i = t; i < cnt; i += BS) buf[i] = packed[p0 + i];
    __syncthreads();
    for (int i = t; i < cnt; i += BS) {
        int v = fits ? buf[i] : packed[p0 + i];
        atomicAdd(&ldeg[((unsigned)v >> 18) & (BIN - 1)], 1);
    }
    __syncthreads();
    // ---- exclusive scan of ldeg[128] via 2-wave shfl scan (1 barrier) ----
    int myDeg = 0, inc = 0;
    if (t < BIN) {
        myDeg = ldeg[t];
        inc = myDeg;
        #pragma unroll
        for (int off = 1; off < 64; off <<= 1) {
            int tmp = __shfl_up(inc, off);
            if (lane >= off) inc += tmp;
        }
        if (lane == 63) wtot[wv] = inc;
    }
    __syncthreads();
    if (t < BIN) {
        int pre = (wv == 1) ? wtot[0] : 0;
        int ex = (inc - myDeg) + pre;
        cur[t] = ex;
        int n = node0 + t;
        if (n < N) {
            row_start[n] = e0 + ex;
            dinv[n] = rsqrtf((float)(myDeg + 1));
        }
    }
    __syncthreads();
    for (int i = t; i < cnt; i += BS) {
        int v = fits ? buf[i] : packed[p0 + i];
        int pos = atomicAdd(&cur[((unsigned)v >> 18) & (BIN - 1)], 1);
        col[e0 + pos] = v & 0x3FFFF;
    }
    // ---- fused mm1: 2 threads per node (16 channels each) ----
    int nl = t & (BIN - 1);
    int half = t >> 7;                           // 0 or 1
    int n = node0 + nl;
    if (n < N) {
        float di = rsqrtf((float)(ldeg[nl] + 1));
        const float4* er = (const float4*)(emb + (size_t)x[n] * 16);
        float4 ra = er[0], rb = er[1], rc = er[2], rd = er[3];
        float ev[16] = {ra.x, ra.y, ra.z, ra.w, rb.x, rb.y, rb.z, rb.w,
                        rc.x, rc.y, rc.z, rc.w, rd.x, rd.y, rd.z, rd.w};
        int4* s1o = (int4*)sig1;
        #pragma unroll
        for (int cq2 = 0; cq2 < 2; cq2++) {
            int cq = half * 2 + cq2;
            H2 pk[4];
            #pragma unroll
            for (int dw = 0; dw < 4; dw++) {
                int c = cq * 8 + dw * 2;
                float acc0 = 0.f, acc1 = 0.f;
                #pragma unroll
                for (int k = 0; k < 16; k++) {
                    acc0 += ev[k] * sW[k * 32 + c];
                    acc1 += ev[k] * sW[k * 32 + c + 1];
                }
                pk[dw].h[0] = (_Float16)(acc0 * di);
                pk[dw].h[1] = (_Float16)(acc1 * di);
            }
            int4 pv;
            pv.x = pk[0].i; pv.y = pk[1].i; pv.z = pk[2].i; pv.w = pk[3].i;
            s1o[(size_t)n * 4 + cq] = pv;
        }
    }
}

// ---- fused layer-1 aggregate + b1 + relu + GEMM W2 -> sig2 (fp16) -----------
// 4 NODES per wave: lane = (node g in [0,4)) x (dword-channel cd in [0,16)).
// PIPELINED: iter k issues group k+1's 8 gathers before consuming group k's
// (col prefetched 2 groups ahead) -> consume waits at vmcnt(9), not drain.
__global__ __launch_bounds__(BS) void k_agg1mm2(
    const _Float16* __restrict__ sig1, const int* __restrict__ row_start,
    const float* __restrict__ dinv, const int* __restrict__ col,
    const float* __restrict__ b1, const float* __restrict__ W2,
    int N, _Float16* __restrict__ sig2) {
    __shared__ float hbuf[4][4][36];   // [wave][node][32 ch + pad]
    int t = threadIdx.x;
    int lane = t & 63;
    int wid = t >> 6;
    int g  = lane >> 4;                // node within wave
    int cd = lane & 15;                // dword channel (2 fp16)
    int n = blockIdx.x * 16 + wid * 4 + g;
    int nld = (n < N) ? n : N - 1;
    int rs = row_start[nld];
    int re = row_start[nld + 1];
    int dn = (n < N) ? (re - rs) : 0;
    int dnm1 = (dn > 0) ? dn - 1 : 0;
    int dm = dn;                       // wave max degree
    dm = max(dm, __shfl_xor(dm, 16));
    dm = max(dm, __shfl_xor(dm, 32));
    const int* s1i = (const int*)sig1;
    float a0 = 0.f, a1 = 0.f;
    int iters = (dm + 7) >> 3;
    int slot = cd & 7;
    int bidx = lane & 48;              // group base lane
    int colv = 0, coln = 0;
    if (iters > 0) {
        int idx = slot; if (idx > dnm1) idx = dnm1;
        colv = col[rs + idx];
    }
    if (iters > 1) {
        int idx = 8 + slot; if (idx > dnm1) idx = dnm1;
        coln = col[rs + idx];
    }
    // prologue: issue group 0's gathers
    int u0 = 0, u1 = 0, u2 = 0, u3 = 0, u4 = 0, u5 = 0, u6 = 0, u7 = 0;
    if (iters > 0) {
        int s0 = __shfl(colv, bidx + 0);
        int s1 = __shfl(colv, bidx + 1);
        int s2 = __shfl(colv, bidx + 2);
        int s3 = __shfl(colv, bidx + 3);
        int s4 = __shfl(colv, bidx + 4);
        int s5 = __shfl(colv, bidx + 5);
        int s6 = __shfl(colv, bidx + 6);
        int s7 = __shfl(colv, bidx + 7);
        u0 = s1i[s0 * 16 + cd];        // 8 rows (64B lines) in flight
        u1 = s1i[s1 * 16 + cd];
        u2 = s1i[s2 * 16 + cd];
        u3 = s1i[s3 * 16 + cd];
        u4 = s1i[s4 * 16 + cd];
        u5 = s1i[s5 * 16 + cd];
        u6 = s1i[s6 * 16 + cd];
        u7 = s1i[s7 * 16 + cd];
    }
    for (int it = 0; it < iters; it++) {
        int colnn = 0;
        if (it + 2 < iters) {
            int idx = ((it + 2) << 3) + slot; if (idx > dnm1) idx = dnm1;
            colnn = col[rs + idx];     // col prefetch 2 groups ahead
        }
        // issue NEXT group's gathers before consuming current
        int v0 = 0, v1 = 0, v2 = 0, v3 = 0, v4 = 0, v5 = 0, v6 = 0, v7 = 0;
        if (it + 1 < iters) {
            int s0 = __shfl(coln, bidx + 0);
            int s1 = __shfl(coln, bidx + 1);
            int s2 = __shfl(coln, bidx + 2);
            int s3 = __shfl(coln, bidx + 3);
            int s4 = __shfl(coln, bidx + 4);
            int s5 = __shfl(coln, bidx + 5);
            int s6 = __shfl(coln, bidx + 6);
            int s7 = __shfl(coln, bidx + 7);
            v0 = s1i[s0 * 16 + cd];
            v1 = s1i[s1 * 16 + cd];
            v2 = s1i[s2 * 16 + cd];
            v3 = s1i[s3 * 16 + cd];
            v4 = s1i[s4 * 16 + cd];
            v5 = s1i[s5 * 16 + cd];
            v6 = s1i[s6 * 16 + cd];
            v7 = s1i[s7 * 16 + cd];
        }
        // consume current group (waits only for u0..u7: vmcnt(9))
        int e = it << 3;
        int w0 = (e + 0 < dn) ? u0 : 0;    // 0x0 == +0.0 fp16 pair
        int w1 = (e + 1 < dn) ? u1 : 0;
        int w2 = (e + 2 < dn) ? u2 : 0;
        int w3 = (e + 3 < dn) ? u3 : 0;
        int w4 = (e + 4 < dn) ? u4 : 0;
        int w5 = (e + 5 < dn) ? u5 : 0;
        int w6 = (e + 6 < dn) ? u6 : 0;
        int w7 = (e + 7 < dn) ? u7 : 0;
        H2 p0, p1, p2, p3;
        p0.i = w0; p1.i = w1; p2.i = w2; p3.i = w3;
        a0 += ((float)p0.h[0] + (float)p1.h[0]) + ((float)p2.h[0] + (float)p3.h[0]);
        a1 += ((float)p0.h[1] + (float)p1.h[1]) + ((float)p2.h[1] + (float)p3.h[1]);
        p0.i = w4; p1.i = w5; p2.i = w6; p3.i = w7;
        a0 += ((float)p0.h[0] + (float)p1.h[0]) + ((float)p2.h[0] + (float)p3.h[0]);
        a1 += ((float)p0.h[1] + (float)p1.h[1]) + ((float)p2.h[1] + (float)p3.h[1]);
        u0 = v0; u1 = v1; u2 = v2; u3 = v3;
        u4 = v4; u5 = v5; u6 = v6; u7 = v7;
        colv = coln; coln = colnn;
    }
    {   // self-loop (pre-scaled row)
        H2 p; p.i = s1i[nld * 16 + cd];
        a0 += (float)p.h[0];
        a1 += (float)p.h[1];
    }
    float di = dinv[nld];
    float2 b = ((const float2*)b1)[cd];
    float h0 = fmaxf(a0 * di + b.x, 0.f);
    float h1 = fmaxf(a1 * di + b.y, 0.f);
    float* hb = hbuf[wid][g];
    *(float2*)&hb[2 * cd] = make_float2(h0, h1);
    // w2c loaded HERE (epilogue-only use; keeps main-loop VGPR pressure low,
    // and the global loads cover the ds_write->ds_read latency)
    float w2c[32];
    #pragma unroll
    for (int k = 0; k < 32; k++) w2c[k] = W2[k * 16 + cd];
    // same-wave LDS produce->consume: in-order ds ops + lgkmcnt, no barrier
    float a = 0.f;
    #pragma unroll
    for (int k = 0; k < 32; k += 4) {
        float4 hv = *(const float4*)&hb[k];
        a = fmaf(hv.x, w2c[k],     a);
        a = fmaf(hv.y, w2c[k + 1], a);
        a = fmaf(hv.z, w2c[k + 2], a);
        a = fmaf(hv.w, w2c[k + 3], a);
    }
    if (n < N) sig2[(size_t)n * 16 + cd] = (_Float16)(a * di);   // pre-scale
}

// ---- layer-2 aggregate + b2 -> out ------------------------------------------
// 4 NODES per wave: lane = (node g) x (edge-half e2) x (dword cd in [0,8)).
// PIPELINED like agg1: next group's 8 gathers issued before consuming current.
__global__ __launch_bounds__(BS) void k_agg2(
    const _Float16* __restrict__ sig2, const int* __restrict__ row_start,
    const float* __restrict__ dinv, const int* __restrict__ col,
    const float* __restrict__ b2, int N, float* __restrict__ out) {
    int t = threadIdx.x;
    int lane = t & 63;
    int g  = lane >> 4;                // node within wave
    int e2 = (lane >> 3) & 1;          // edge half
    int cd = lane & 7;                 // dword channel (2 fp16)
    int n = blockIdx.x * 16 + (t >> 6) * 4 + g;
    int nld = (n < N) ? n : N - 1;
    int rs = row_start[nld];
    int re = row_start[nld + 1];
    int dn = (n < N) ? (re - rs) : 0;
    int dnm1 = (dn > 0) ? dn - 1 : 0;
    int dm = dn;
    dm = max(dm, __shfl_xor(dm, 16));
    dm = max(dm, __shfl_xor(dm, 32));
    const int* s2i = (const int*)sig2;
    float a0 = 0.f, a1 = 0.f;
    int iters = (dm + 15) >> 4;
    int slot = lane & 15;              // this lane's col slot (0..15)
    int bidx = lane & 48;
    int colv = 0, coln = 0;
    if (iters > 0) {
        int idx = slot; if (idx > dnm1) idx = dnm1;
        colv = col[rs + idx];
    }
    if (iters > 1) {
        int idx = 16 + slot; if (idx > dnm1) idx = dnm1;
        coln = col[rs + idx];
    }
    // prologue: issue group 0's gathers (8 per lane; each inst = 8 rows)
    int u0 = 0, u1 = 0, u2 = 0, u3 = 0, u4 = 0, u5 = 0, u6 = 0, u7 = 0;
    if (iters > 0) {
        int s0 = __shfl(colv, bidx + 0 + e2);
        int s1 = __shfl(colv, bidx + 2 + e2);
        int s2 = __shfl(colv, bidx + 4 + e2);
        int s3 = __shfl(colv, bidx + 6 + e2);
        int s4 = __shfl(colv, bidx + 8 + e2);
        int s5 = __shfl(colv, bidx + 10 + e2);
        int s6 = __shfl(colv, bidx + 12 + e2);
        int s7 = __shfl(colv, bidx + 14 + e2);
        u0 = s2i[s0 * 8 + cd];
        u1 = s2i[s1 * 8 + cd];
        u2 = s2i[s2 * 8 + cd];
        u3 = s2i[s3 * 8 + cd];
        u4 = s2i[s4 * 8 + cd];
        u5 = s2i[s5 * 8 + cd];
        u6 = s2i[s6 * 8 + cd];
        u7 = s2i[s7 * 8 + cd];
    }
    for (int it = 0; it < iters; it++) {
        int colnn = 0;
        if (it + 2 < iters) {
            int idx = ((it + 2) << 4) + slot; if (idx > dnm1) idx = dnm1;
            colnn = col[rs + idx];     // col prefetch 2 groups ahead
        }
        int v0 = 0, v1 = 0, v2 = 0, v3 = 0, v4 = 0, v5 = 0, v6 = 0, v7 = 0;
        if (it + 1 < iters) {
            int s0 = __shfl(coln, bidx + 0 + e2);
            int s1 = __shfl(coln, bidx + 2 + e2);
            int s2 = __shfl(coln, bidx + 4 + e2);
            int s3 = __shfl(coln, bidx + 6 + e2);
            int s4 = __shfl(coln, bidx + 8 + e2);
            int s5 = __shfl(coln, bidx + 10 + e2);
            int s6 = __shfl(coln, bidx + 12 + e2);
            int s7 = __shfl(coln, bidx + 14 + e2);
            v0 = s2i[s0 * 8 + cd];
            v1 = s2i[s1 * 8 + cd];
            v2 = s2i[s2 * 8 + cd];
            v3 = s2i[s3 * 8 + cd];
            v4 = s2i[s4 * 8 + cd];
            v5 = s2i[s5 * 8 + cd];
            v6 = s2i[s6 * 8 + cd];
            v7 = s2i[s7 * 8 + cd];
        }
        int e = it << 4;
        int w0 = (e + 0  + e2 < dn) ? u0 : 0;
        int w1 = (e + 2  + e2 < dn) ? u1 : 0;
        int w2 = (e + 4  + e2 < dn) ? u2 : 0;
        int w3 = (e + 6  + e2 < dn) ? u3 : 0;
        int w4 = (e + 8  + e2 < dn) ? u4 : 0;
        int w5 = (e + 10 + e2 < dn) ? u5 : 0;
        int w6 = (e + 12 + e2 < dn) ? u6 : 0;
        int w7 = (e + 14 + e2 < dn) ? u7 : 0;
        H2 p0, p1, p2, p3;
        p0.i = w0; p1.i = w1; p2.i = w2; p3.i = w3;
        a0 += ((float)p0.h[0] + (float)p1.h[0]) + ((float)p2.h[0] + (float)p3.h[0]);
        a1 += ((float)p0.h[1] + (float)p1.h[1]) + ((float)p2.h[1] + (float)p3.h[1]);
        p0.i = w4; p1.i = w5; p2.i = w6; p3.i = w7;
        a0 += ((float)p0.h[0] + (float)p1.h[0]) + ((float)p2.h[0] + (float)p3.h[0]);
        a1 += ((float)p0.h[1] + (float)p1.h[1]) + ((float)p2.h[1] + (float)p3.h[1]);
        u0 = v0; u1 = v1; u2 = v2; u3 = v3;
        u4 = v4; u5 = v5; u6 = v6; u7 = v7;
        colv = coln; coln = colnn;
    }
    a0 += __shfl_xor(a0, 8);           // combine edge halves
    a1 += __shfl_xor(a1, 8);
    {   // self-loop
        H2 p; p.i = s2i[nld * 8 + cd];
        a0 += (float)p.h[0];
        a1 += (float)p.h[1];
    }
    if (n < N && e2 == 0) {
        float di = dinv[nld];
        float2 b = ((const float2*)b2)[cd];
        float2 o;
        o.x = a0 * di + b.x;
        o.y = a1 * di + b.y;
        ((float2*)out)[(size_t)n * 8 + cd] = o;
    }
}

extern "C" void kernel_launch(void* const* d_in, const int* in_sizes, int n_in,
                              void* d_out, int out_size, void* d_ws, size_t ws_size,
                              hipStream_t stream) {
    const int*   x   = (const int*)d_in[0];
    const int*   ei  = (const int*)d_in[1];
    const float* emb = (const float*)d_in[2];
    const float* W1  = (const float*)d_in[3];
    const float* b1  = (const float*)d_in[4];
    const float* W2  = (const float*)d_in[5];
    const float* b2  = (const float*)d_in[6];
    float* out = (float*)d_out;

    const int N = in_sizes[0];
    const int E = in_sizes[1] / 2;
    const int* srcp = ei;
    const int* dstp = ei + E;
    const int NBINS = (N + BIN - 1) >> BINSHIFT;   // 782 for N=100000

    auto al = [](size_t b) { return (b + 255) & ~size_t(255); };
    char* w = (char*)d_ws;
    auto carve = [&](size_t bytes) {
        void* p = (void*)w;
        w += al(bytes);
        return p;
    };
    // no unions: binsort writes sig1 while other blocks still read packed.
    int*   row_start = (int*)carve((size_t)(N + 1) * 4);
    float* dinv      = (float*)carve((size_t)N * 4);
    int*   col       = (int*)carve((size_t)(E + 256) * 4);  // +pad for clamped reads
    int*   gbin      = (int*)carve((size_t)NBINS * 4);
    int*   packed    = (int*)carve((size_t)NBINS * BINSTRIDE * 4);
    _Float16* sig1   = (_Float16*)carve((size_t)N * 32 * 2);
    _Float16* sig2   = (_Float16*)carve((size_t)N * 16 * 2);
    (void)ws_size; (void)n_in; (void)out_size;

    hipMemsetAsync(gbin, 0, (size_t)NBINS * 4, stream);
    k_scatter<<<NBLK, BSBIG, 0, stream>>>(srcp, dstp, E, NBINS, gbin, packed);
    k_binsort<<<NBINS, BS, 0, stream>>>(packed, gbin, NBINS, N, E,
                                        x, emb, W1, row_start, dinv, col, sig1);

    int gA = (N + 15) / 16;            // 4 waves x 4 nodes per block
    k_agg1mm2<<<gA, BS, 0, stream>>>(sig1, row_start, dinv, col, b1, W2, N, sig2);
    k_agg2<<<gA, BS, 0, stream>>>(sig2, row_start, dinv, col, b2, N, out);
}